// Round 7
// baseline (1727.906 us; speedup 1.0000x reference)
//
#include <hip/hip_runtime.h>
#include <math.h>

#define B_ 2
#define T_ 512
#define DM_ 1024
#define DH_ 4096
#define DD_ 4
#define V_ 32000
#define M_ 4096      // B*T*DD
#define BT_ 1024     // B*T
#define NCHUNK3_ 125 // V_/256
#define PCH_ 128     // pmax/psum row stride
#define NB1_ 16      // DH_/256 beta chunks

typedef __attribute__((ext_vector_type(8))) unsigned short ushort8_t;
typedef __attribute__((ext_vector_type(4))) unsigned short ushort4_t;
typedef __attribute__((ext_vector_type(8))) __bf16 bf16x8;
typedef __attribute__((ext_vector_type(4))) float f32x4;

__device__ __forceinline__ unsigned short f2bf(float x) {
  union { float f; unsigned u; } v; v.f = x;
  unsigned r = v.u + 0x7fffu + ((v.u >> 16) & 1u);
  return (unsigned short)(r >> 16);
}
__device__ __forceinline__ float bf2f(unsigned short h) {
  union { unsigned u; float f; } v; v.u = ((unsigned)h) << 16; return v.f;
}

__device__ __forceinline__ void gload16(const void* g, void* l) {
  __builtin_amdgcn_global_load_lds(
      (const __attribute__((address_space(1))) void*)g,
      (__attribute__((address_space(3))) void*)l, 16, 0, 0);
}

__device__ __forceinline__ float block_sum256(float v, float* sh) {
  #pragma unroll
  for (int o = 32; o >= 1; o >>= 1) v += __shfl_down(v, o);
  int lane = threadIdx.x & 63, wid = threadIdx.x >> 6;
  if (lane == 0) sh[wid] = v;
  __syncthreads();
  float t = sh[0] + sh[1] + sh[2] + sh[3];
  __syncthreads();
  return t;
}

// ---------------- small prep kernels (unchanged) ----------------

__global__ __launch_bounds__(256) void transpose_split_kernel(
    const float* __restrict__ in, int R, int C,
    unsigned short* __restrict__ out_hi, unsigned short* __restrict__ out_lo)
{
  __shared__ float tile[32][33];
  int c0 = blockIdx.x * 32, r0 = blockIdx.y * 32;
  int tx = threadIdx.x & 31, ty = threadIdx.x >> 5;
  #pragma unroll
  for (int i = 0; i < 4; ++i)
    tile[ty + i * 8][tx] = in[(size_t)(r0 + ty + i * 8) * C + c0 + tx];
  __syncthreads();
  #pragma unroll
  for (int i = 0; i < 4; ++i) {
    int orow = c0 + ty + i * 8;
    int ocol = r0 + tx;
    float v = tile[tx][ty + i * 8];
    unsigned short h = f2bf(v);
    out_hi[(size_t)orow * R + ocol] = h;
    if (out_lo) out_lo[(size_t)orow * R + ocol] = f2bf(v - bf2f(h));
  }
}

__global__ __launch_bounds__(256) void embed_ln_kernel(
    const float* __restrict__ H, const int* __restrict__ ids,
    const float* __restrict__ emb, const float* __restrict__ demb,
    const float* __restrict__ g, const float* __restrict__ be,
    unsigned short* __restrict__ Xhi, unsigned short* __restrict__ Xlo)
{
  __shared__ float sh[8];
  int m = blockIdx.x, tid = threadIdx.x;
  int bt = m >> 2, d = m & 3;
  int id = ids[bt];
  float4 x  = ((const float4*)(H   + (size_t)bt * DM_))[tid];
  float4 e  = ((const float4*)(emb + (size_t)id * DM_))[tid];
  float4 de = ((const float4*)(demb + (size_t)d * DM_))[tid];
  float v0 = x.x + e.x + de.x, v1 = x.y + e.y + de.y;
  float v2 = x.z + e.z + de.z, v3 = x.w + e.w + de.w;
  float mu = block_sum256((v0 + v1) + (v2 + v3), sh) * (1.0f / DM_);
  float d0 = v0 - mu, d1v = v1 - mu, d2 = v2 - mu, d3 = v3 - mu;
  float var = block_sum256((d0 * d0 + d1v * d1v) + (d2 * d2 + d3 * d3), sh) * (1.0f / DM_);
  float rs = rsqrtf(var + 1e-5f);
  float4 gg  = ((const float4*)g)[tid];
  float4 bb4 = ((const float4*)be)[tid];
  float y0 = d0 * rs * gg.x + bb4.x;
  float y1 = d1v * rs * gg.y + bb4.y;
  float y2 = d2 * rs * gg.z + bb4.z;
  float y3 = d3 * rs * gg.w + bb4.w;
  unsigned short h0 = f2bf(y0), h1 = f2bf(y1), h2 = f2bf(y2), h3 = f2bf(y3);
  ushort4_t hv = {h0, h1, h2, h3};
  ushort4_t lv = {f2bf(y0 - bf2f(h0)), f2bf(y1 - bf2f(h1)), f2bf(y2 - bf2f(h2)), f2bf(y3 - bf2f(h3))};
  size_t base = (size_t)m * DM_ + tid * 4;
  *(ushort4_t*)&Xhi[base] = hv;
  *(ushort4_t*)&Xlo[base] = lv;
}

__global__ __launch_bounds__(64) void w2b_kernel(
    const float* __restrict__ W2, const float* __restrict__ Wb,
    const float* __restrict__ b2, const float* __restrict__ bb,
    float* __restrict__ w2b)
{
  int j = blockIdx.x, lane = threadIdx.x;
  const float* rowp = (j < DH_) ? (W2 + (size_t)j * DM_) : b2;
  const float4* r4 = (const float4*)rowp;
  const float4* w4 = (const float4*)Wb;
  float s = 0.0f;
  for (int i = lane; i < DM_ / 4; i += 64) {
    float4 a = r4[i], w = w4[i];
    s += a.x * w.x + a.y * w.y + a.z * w.z + a.w * w.w;
  }
  #pragma unroll
  for (int o = 32; o >= 1; o >>= 1) s += __shfl_down(s, o);
  if (lane == 0) w2b[j] = (j < DH_) ? s : (s + bb[0]);
}

// ---------------- gemm3p (kept for GEMM2) ----------------

template<int ROWS, int NWAVE>
__device__ __forceinline__ void stage_swz(const unsigned short* __restrict__ src, int ld,
                                          unsigned short* lds, int wid, int lane) {
  constexpr int NLOAD = ROWS / (16 * NWAVE);
  const int rl = lane >> 2;
  const int slot = (lane & 3) ^ ((lane >> 3) & 3);
  #pragma unroll
  for (int i = 0; i < NLOAD; ++i) {
    const int rbase = (i * NWAVE + wid) * 16;
    gload16(src + (size_t)(rbase + rl) * ld + slot * 8, lds + rbase * 32);
  }
}
__device__ __forceinline__ bf16x8 ldfrag(const unsigned short* t, int r, int s) {
  return __builtin_bit_cast(bf16x8,
      *(const ushort8_t*)&t[r * 32 + ((s ^ ((r >> 1) & 3)) * 8)]);
}

template<int BM, int BN, int NWAVE, int WN>
__global__ __launch_bounds__(NWAVE * 64, 2) void gemm3p_kernel(
    const unsigned short* __restrict__ Ahi,
    const unsigned short* __restrict__ Bhi,
    const float* __restrict__ bias, int Ndim, int Kdim,
    unsigned short* __restrict__ Chi)
{
  constexpr int WM = NWAVE / WN;
  constexpr int MI = (BM / WM) / 16;
  constexpr int NI = (BN / WN) / 16;
  constexpr int AW = BM * 32;
  constexpr int BW = BN * 32;
  constexpr int BUFW = AW + BW;
  constexpr int LPS = (BM / (16 * NWAVE) + BN / (16 * NWAVE));
  static_assert(LPS * NWAVE * 16 == BM + BN, "");
  __shared__ __align__(16) unsigned short smem[3 * BUFW];

  const int m0 = blockIdx.x * BM, n0 = blockIdx.y * BN;
  const int tid = threadIdx.x, lane = tid & 63, wid = tid >> 6;
  const int wr = wid / WN, wc = wid % WN;
  const int lrow = lane & 15, q4 = lane >> 4;
  const int wrb = wr * (BM / WM), wcb = wc * (BN / WN);

  const unsigned short* Ab = Ahi + (size_t)m0 * Kdim;
  const unsigned short* Bb = Bhi + (size_t)n0 * Kdim;

  f32x4 acc[MI][NI] = {};
  const int NT = Kdim / 32;

  auto stageAll = [&](unsigned short* base, int kt) {
    const int ko = kt * 32;
    stage_swz<BM, NWAVE>(Ab + ko, Kdim, base, wid, lane);
    stage_swz<BN, NWAVE>(Bb + ko, Kdim, base + AW, wid, lane);
  };

  unsigned short* p0 = smem;
  unsigned short* p1 = smem + BUFW;
  unsigned short* p2 = smem + 2 * BUFW;
  stageAll(p0, 0);
  stageAll(p1, 1);

  for (int kt = 0; kt < NT; ++kt) {
    if (kt + 1 < NT) asm volatile("s_waitcnt vmcnt(4)" ::: "memory");
    else             asm volatile("s_waitcnt vmcnt(0)" ::: "memory");
    __builtin_amdgcn_s_barrier();
    __builtin_amdgcn_sched_barrier(0);
    if (kt + 2 < NT) stageAll(p2, kt + 2);
    __builtin_amdgcn_sched_barrier(0);
    const unsigned short* sA = p0;
    const unsigned short* sB = p0 + AW;
    bf16x8 bh[NI];
    #pragma unroll
    for (int ni = 0; ni < NI; ++ni) bh[ni] = ldfrag(sB, wcb + ni * 16 + lrow, q4);
    #pragma unroll
    for (int mi = 0; mi < MI; ++mi) {
      bf16x8 ah = ldfrag(sA, wrb + mi * 16 + lrow, q4);
      #pragma unroll
      for (int ni = 0; ni < NI; ++ni)
        acc[mi][ni] = __builtin_amdgcn_mfma_f32_16x16x32_bf16(ah, bh[ni], acc[mi][ni], 0, 0, 0);
    }
    unsigned short* t = p0; p0 = p1; p1 = p2; p2 = t;
  }

  #pragma unroll
  for (int mi = 0; mi < MI; ++mi)
    #pragma unroll
    for (int ni = 0; ni < NI; ++ni) {
      const int col = n0 + wcb + ni * 16 + lrow;
      const float bv = bias ? bias[col] : 0.0f;
      #pragma unroll
      for (int r2 = 0; r2 < 4; ++r2) {
        const int gm = m0 + wrb + mi * 16 + q4 * 4 + r2;
        float v = acc[mi][ni][r2] + bv;
        Chi[(size_t)gm * Ndim + col] = f2bf(v);
      }
    }
}

// ---------------- 8-phase 256x256 BK=64 GEMM (m201-style port) ----------------
// C = A @ B^T (+bias)(+GELU). A,B row-major (rows x K), K segmented in 1024-col
// chunks: source pointer for K-tile kt is seg[kt>>4] (enables the split-GEMM-as-
// K-concat trick without materializing).  8 waves (2Mx4N), 2 K-tiles/iteration,
// 8 phases: {ds_read subtile | stage 1 half-tile} -> barrier -> lgkmcnt(0) ->
// 16 MFMA -> barrier.  vmcnt(4) only at phases 1 and 5.  LDS row-XOR swizzle
// slot^=(r&7) applied on global source (staging) and on ds_read (rule 21).
template<bool GELU, bool CEPART, bool BETAPART, bool NTC>
__global__ __launch_bounds__(512, 2) void gemm8p_kernel(
    const unsigned short* __restrict__ A0s, const unsigned short* __restrict__ A1s,
    const unsigned short* __restrict__ A2s,
    const unsigned short* __restrict__ B0s, const unsigned short* __restrict__ B1s,
    const unsigned short* __restrict__ B2s,
    const float* __restrict__ bias, int Ndim, int Kdim,
    float* __restrict__ Cf, unsigned short* __restrict__ Chi, unsigned short* __restrict__ Clo,
    const int* __restrict__ rowmask,
    const float* __restrict__ w2bv, float* __restrict__ bpart,
    float* __restrict__ pmax, float* __restrict__ psum)
{
  __shared__ __align__(16) unsigned short smem[65536];   // 128 KiB: 2 bufs x (A 16K | B 16K) ushorts

  const int m0 = blockIdx.x * 256, n0 = blockIdx.y * 256;
  const int tid = threadIdx.x, lane = tid & 63, wid = tid >> 6;
  const int wr = wid >> 2, wc = wid & 3;           // 2 x 4 waves
  const int lrow = lane & 15, q4 = lane >> 4;
  const int wrb = wr * 128, wcb = wc * 64;
  const int NKT = Kdim >> 6, NIT = NKT >> 1, HT_END = NKT << 2;

  // staging constants: 2 gloads/wave/half-tile; 8 rows per gload (128B rows)
  const int rs = lane >> 3;
  const int cs8 = ((lane & 7) ^ rs) * 8;            // pre-swizzled src col (elems)
  // frag-read constants: slot' = (ks*4+q4) ^ (lrow&7)
  const int sx0 = (q4 ^ (lrow & 7)) * 8;
  const int sx1 = ((4 + q4) ^ (lrow & 7)) * 8;
  const int abase = (wrb + lrow) * 64;              // A region at buf+0
  const int bbase = 16384 + (wcb + lrow) * 64;      // B region at buf+16384

  auto ld8 = [&](int off) {
    return __builtin_bit_cast(bf16x8, *(const ushort8_t*)&smem[off]);
  };
  // half-tile h: kt=h>>2, part: 0=B_lo 1=B_hi 2=A_lo 3=A_hi
  auto stage_ht = [&](int h) {
    if (h >= HT_END) return;
    const int kt = h >> 2, part = h & 3;
    const int seg = kt >> 4, kc = (kt & 15) << 6;
    const unsigned short* mat;
    if (part & 2) mat = (seg == 0) ? A0s : ((seg == 1) ? A1s : A2s);
    else          mat = (seg == 0) ? B0s : ((seg == 1) ? B1s : B2s);
    const int row = ((part & 2) ? m0 : n0) + ((part & 1) << 7) + wid * 16 + rs;
    const unsigned short* g = mat + (size_t)row * 1024 + kc + cs8;
    unsigned short* d = smem + ((kt & 1) << 15)
                      + ((part & 2) ? ((part & 1) << 13) : (16384 + ((part & 1) << 13)))
                      + wid * 1024;
    gload16(g, d);
    gload16(g + (size_t)(8 * 1024), d + 512);
  };

  f32x4 acc[8][4] = {};
  bf16x8 a[4][2], b0[2][2], b1[2][2];

  int hnext = 6;
  #pragma unroll
  for (int h = 0; h < 6; ++h) stage_ht(h);
  asm volatile("s_waitcnt vmcnt(4)" ::: "memory");
  __builtin_amdgcn_s_barrier();

  for (int i = 0; i < NIT; ++i) {
    #pragma unroll
    for (int half = 0; half < 2; ++half) {
      const int kb = half << 15;
      // ---- Phase 1/5: read A(mi0-3) + B(ni0-1); MFMA quad (mi0-3 x ni0-1)
      if (half == 0 || i + 1 < NIT) { asm volatile("s_waitcnt vmcnt(4)" ::: "memory"); }
      else                          { asm volatile("s_waitcnt vmcnt(0)" ::: "memory"); }
      #pragma unroll
      for (int mi = 0; mi < 4; ++mi) {
        a[mi][0] = ld8(kb + abase + mi * 1024 + sx0);
        a[mi][1] = ld8(kb + abase + mi * 1024 + sx1);
      }
      #pragma unroll
      for (int ni = 0; ni < 2; ++ni) {
        b0[ni][0] = ld8(kb + bbase + ni * 1024 + sx0);
        b0[ni][1] = ld8(kb + bbase + ni * 1024 + sx1);
      }
      stage_ht(hnext++);
      __builtin_amdgcn_sched_barrier(0);
      __builtin_amdgcn_s_barrier();
      asm volatile("s_waitcnt lgkmcnt(0)" ::: "memory");
      __builtin_amdgcn_sched_barrier(0);
      __builtin_amdgcn_s_setprio(1);
      #pragma unroll
      for (int mi = 0; mi < 4; ++mi)
        #pragma unroll
        for (int ni = 0; ni < 2; ++ni) {
          acc[mi][ni] = __builtin_amdgcn_mfma_f32_16x16x32_bf16(a[mi][0], b0[ni][0], acc[mi][ni], 0, 0, 0);
          acc[mi][ni] = __builtin_amdgcn_mfma_f32_16x16x32_bf16(a[mi][1], b0[ni][1], acc[mi][ni], 0, 0, 0);
        }
      __builtin_amdgcn_s_setprio(0);
      __builtin_amdgcn_sched_barrier(0);
      __builtin_amdgcn_s_barrier();
      // ---- Phase 2/6: read B(ni2-3); MFMA (mi0-3 x ni2-3)
      #pragma unroll
      for (int ni = 0; ni < 2; ++ni) {
        b1[ni][0] = ld8(kb + bbase + (2 + ni) * 1024 + sx0);
        b1[ni][1] = ld8(kb + bbase + (2 + ni) * 1024 + sx1);
      }
      stage_ht(hnext++);
      __builtin_amdgcn_sched_barrier(0);
      __builtin_amdgcn_s_barrier();
      asm volatile("s_waitcnt lgkmcnt(0)" ::: "memory");
      __builtin_amdgcn_sched_barrier(0);
      __builtin_amdgcn_s_setprio(1);
      #pragma unroll
      for (int mi = 0; mi < 4; ++mi)
        #pragma unroll
        for (int ni = 0; ni < 2; ++ni) {
          acc[mi][2 + ni] = __builtin_amdgcn_mfma_f32_16x16x32_bf16(a[mi][0], b1[ni][0], acc[mi][2 + ni], 0, 0, 0);
          acc[mi][2 + ni] = __builtin_amdgcn_mfma_f32_16x16x32_bf16(a[mi][1], b1[ni][1], acc[mi][2 + ni], 0, 0, 0);
        }
      __builtin_amdgcn_s_setprio(0);
      __builtin_amdgcn_sched_barrier(0);
      __builtin_amdgcn_s_barrier();
      // ---- Phase 3/7: read A(mi4-7); MFMA (mi4-7 x ni2-3)
      #pragma unroll
      for (int mi = 0; mi < 4; ++mi) {
        a[mi][0] = ld8(kb + abase + (4 + mi) * 1024 + sx0);
        a[mi][1] = ld8(kb + abase + (4 + mi) * 1024 + sx1);
      }
      stage_ht(hnext++);
      __builtin_amdgcn_sched_barrier(0);
      __builtin_amdgcn_s_barrier();
      asm volatile("s_waitcnt lgkmcnt(0)" ::: "memory");
      __builtin_amdgcn_sched_barrier(0);
      __builtin_amdgcn_s_setprio(1);
      #pragma unroll
      for (int mi = 0; mi < 4; ++mi)
        #pragma unroll
        for (int ni = 0; ni < 2; ++ni) {
          acc[4 + mi][2 + ni] = __builtin_amdgcn_mfma_f32_16x16x32_bf16(a[mi][0], b1[ni][0], acc[4 + mi][2 + ni], 0, 0, 0);
          acc[4 + mi][2 + ni] = __builtin_amdgcn_mfma_f32_16x16x32_bf16(a[mi][1], b1[ni][1], acc[4 + mi][2 + ni], 0, 0, 0);
        }
      __builtin_amdgcn_s_setprio(0);
      __builtin_amdgcn_sched_barrier(0);
      __builtin_amdgcn_s_barrier();
      // ---- Phase 4/8: no reads (A from P3 regs, B0 from P1 regs); MFMA (mi4-7 x ni0-1)
      stage_ht(hnext++);
      __builtin_amdgcn_sched_barrier(0);
      __builtin_amdgcn_s_barrier();
      __builtin_amdgcn_s_setprio(1);
      #pragma unroll
      for (int mi = 0; mi < 4; ++mi)
        #pragma unroll
        for (int ni = 0; ni < 2; ++ni) {
          acc[4 + mi][ni] = __builtin_amdgcn_mfma_f32_16x16x32_bf16(a[mi][0], b0[ni][0], acc[4 + mi][ni], 0, 0, 0);
          acc[4 + mi][ni] = __builtin_amdgcn_mfma_f32_16x16x32_bf16(a[mi][1], b0[ni][1], acc[4 + mi][ni], 0, 0, 0);
        }
      __builtin_amdgcn_s_setprio(0);
      __builtin_amdgcn_sched_barrier(0);
      __builtin_amdgcn_s_barrier();
    }
  }

  // ---- epilogue ----
  #pragma unroll
  for (int mi = 0; mi < 8; ++mi)
    #pragma unroll
    for (int ni = 0; ni < 4; ++ni) {
      const int col = n0 + wcb + ni * 16 + lrow;
      const float bv = bias ? bias[col] : 0.0f;
      #pragma unroll
      for (int r2 = 0; r2 < 4; ++r2) {
        const int gm = m0 + wrb + mi * 16 + q4 * 4 + r2;
        float v = acc[mi][ni][r2] + bv;
        if constexpr (GELU) v = 0.5f * v * (1.0f + erff(v * 0.70710678118654752440f));
        if (rowmask) v *= (rowmask[gm >> 2] ? 1.0f : 0.0f);
        acc[mi][ni][r2] = v;
        const size_t idx = (size_t)gm * Ndim + col;
        if (Cf) {
          if constexpr (NTC) __builtin_nontemporal_store(v, &Cf[idx]);
          else Cf[idx] = v;
        }
        if (Chi) {
          unsigned short h = f2bf(v);
          Chi[idx] = h;
          if (Clo) Clo[idx] = f2bf(v - bf2f(h));
        }
      }
    }

  float* red = (float*)smem;

  if constexpr (CEPART) {
    __syncthreads();
    #pragma unroll
    for (int mi = 0; mi < 8; ++mi)
      #pragma unroll
      for (int r2 = 0; r2 < 4; ++r2) {
        float mx = -3.4e38f;
        #pragma unroll
        for (int ni = 0; ni < 4; ++ni) mx = fmaxf(mx, acc[mi][ni][r2]);
        #pragma unroll
        for (int o = 1; o < 16; o <<= 1) mx = fmaxf(mx, __shfl_xor(mx, o));
        float sm = 0.0f;
        #pragma unroll
        for (int ni = 0; ni < 4; ++ni) sm += expf(acc[mi][ni][r2] - mx);
        #pragma unroll
        for (int o = 1; o < 16; o <<= 1) sm += __shfl_xor(sm, o);
        if (lrow == 0) {
          const int rowL = wrb + mi * 16 + q4 * 4 + r2;
          red[(rowL * 4 + wc) * 2 + 0] = mx;
          red[(rowL * 4 + wc) * 2 + 1] = sm;
        }
      }
    __syncthreads();
    for (int r = tid; r < 256; r += 512) {
      float mg = -3.4e38f, sg = 0.0f;
      #pragma unroll
      for (int w = 0; w < 4; ++w) {
        float mw = red[(r * 4 + w) * 2 + 0], sw = red[(r * 4 + w) * 2 + 1];
        float nm = fmaxf(mg, mw);
        sg = sg * expf(mg - nm) + sw * expf(mw - nm);
        mg = nm;
      }
      pmax[(size_t)(m0 + r) * PCH_ + blockIdx.y] = mg;
      psum[(size_t)(m0 + r) * PCH_ + blockIdx.y] = sg;
    }
  }

  if constexpr (BETAPART) {
    __syncthreads();
    #pragma unroll
    for (int mi = 0; mi < 8; ++mi)
      #pragma unroll
      for (int r2 = 0; r2 < 4; ++r2) {
        float s = 0.0f;
        #pragma unroll
        for (int ni = 0; ni < 4; ++ni)
          s += acc[mi][ni][r2] * w2bv[n0 + wcb + ni * 16 + lrow];
        #pragma unroll
        for (int o = 1; o < 16; o <<= 1) s += __shfl_xor(s, o);
        if (lrow == 0)
          red[(wrb + mi * 16 + q4 * 4 + r2) * 4 + wc] = s;
      }
    __syncthreads();
    for (int r = tid; r < 256; r += 512) {
      float s = red[r * 4 + 0] + red[r * 4 + 1] + red[r * 4 + 2] + red[r * 4 + 3];
      bpart[(size_t)(m0 + r) * 32 + blockIdx.y] = s;
    }
  }
}

// ---------------- tail kernels ----------------

__global__ __launch_bounds__(64) void beta_k_kernel(
    const float* __restrict__ bpart, const float* __restrict__ w2b,
    const int* __restrict__ mask,
    float* __restrict__ beta_out, float* __restrict__ k_out,
    float* __restrict__ bce, int* __restrict__ validf)
{
  int m = blockIdx.x, lane = threadIdx.x;
  float s = (lane < NB1_) ? bpart[(size_t)m * 32 + lane] : 0.0f;
  #pragma unroll
  for (int o = 32; o >= 1; o >>= 1) s += __shfl_down(s, o);
  if (lane == 0) {
    int bt = m >> 2, d1 = (m & 3) + 1;
    float beta = s + w2b[DH_];
    int mv = mask[bt];
    float bm = mv ? beta : 0.0f;
    int t = bt % T_;
    int valid = (t + d1 < T_) && mv && mask[bt + d1];
    beta_out[m] = bm;
    float sp = fmaxf(bm, 0.0f) + log1pf(expf(-fabsf(bm)));
    bce[m] = sp - (valid ? bm : 0.0f);
    validf[m] = valid;
    float sig = 1.0f / (1.0f + expf(-bm));
    int kk = (int)ceilf(sig * 8.0f);
    kk = kk < 1 ? 1 : (kk > 8 ? 8 : kk);
    if (!(sig >= 0.25f)) kk = 0;
    if (!mv) kk = 0;
    k_out[m] = (float)kk;
  }
}

__global__ __launch_bounds__(64) void ce_reduce_kernel(
    const float* __restrict__ pmax, const float* __restrict__ psum,
    const float* __restrict__ q, const int* __restrict__ validf,
    const int* __restrict__ labels, float* __restrict__ nll)
{
  int m = blockIdx.x, lane = threadIdx.x;
  if (!validf[m]) { if (lane == 0) nll[m] = 0.0f; return; }
  float ml = -3.4e38f, sl = 0.0f;
  for (int j = lane; j < NCHUNK3_; j += 64) {
    float mj = pmax[(size_t)m * PCH_ + j], sj = psum[(size_t)m * PCH_ + j];
    float nm = fmaxf(ml, mj);
    sl = sl * expf(ml - nm) + sj * expf(mj - nm);
    ml = nm;
  }
  #pragma unroll
  for (int o = 32; o >= 1; o >>= 1) {
    float mo = __shfl_xor(ml, o), so = __shfl_xor(sl, o);
    float nm = fmaxf(ml, mo);
    sl = sl * expf(ml - nm) + so * expf(mo - nm);
    ml = nm;
  }
  if (lane == 0) {
    int bt = m >> 2, d1 = (m & 3) + 1;
    float qt = q[(size_t)m * V_ + labels[bt + d1]];
    nll[m] = -(qt - ml - logf(sl));
  }
}

__global__ __launch_bounds__(256) void loss_kernel(
    const float* __restrict__ nll, const int* __restrict__ validf,
    const float* __restrict__ bce, float* __restrict__ loss_out)
{
  __shared__ float sh[8];
  int tid = threadIdx.x;
  float snll = 0.0f, fcnt = 0.0f, sbce = 0.0f, fnsrc = 0.0f;
  for (int m = tid; m < M_; m += 256) { snll += nll[m]; fcnt += (float)validf[m]; }
  for (int bt = tid; bt < BT_; bt += 256) {
    int base = bt * 4;
    int src = validf[base] | validf[base + 1] | validf[base + 2] | validf[base + 3];
    if (src) { sbce += bce[base] + bce[base + 1] + bce[base + 2] + bce[base + 3]; fnsrc += 1.0f; }
  }
  snll = block_sum256(snll, sh);
  fcnt = block_sum256(fcnt, sh);
  sbce = block_sum256(sbce, sh);
  fnsrc = block_sum256(fnsrc, sh);
  if (tid == 0) {
    float Lq = fcnt > 0.0f ? snll / fcnt : 0.0f;
    float Lb = sbce / fmaxf(fnsrc, 1.0f);
    loss_out[0] = Lq + Lb;
  }
}

extern "C" void kernel_launch(void* const* d_in, const int* in_sizes, int n_in,
                              void* d_out, int out_size, void* d_ws, size_t ws_size,
                              hipStream_t stream) {
  const float* H    = (const float*)d_in[0];
  const int*   ids  = (const int*)d_in[1];
  const int*   mask = (const int*)d_in[2];
  const int*   labels = (const int*)d_in[3];
  const float* emb  = (const float*)d_in[4];
  const float* demb = (const float*)d_in[5];
  const float* ln_g = (const float*)d_in[6];
  const float* ln_b = (const float*)d_in[7];
  const float* W1   = (const float*)d_in[8];
  const float* b1   = (const float*)d_in[9];
  const float* W2   = (const float*)d_in[10];
  const float* b2   = (const float*)d_in[11];
  const float* Wq   = (const float*)d_in[12];
  const float* bq   = (const float*)d_in[13];
  const float* Wb   = (const float*)d_in[14];
  const float* bb   = (const float*)d_in[15];

  char* ws = (char*)d_ws; size_t off = 0;
  auto walloc = [&](size_t bytes) -> void* {
    void* p = ws + off; off = (off + bytes + 255) & ~(size_t)255; return p;
  };
  unsigned short* W1t_hi = (unsigned short*)walloc((size_t)DH_ * DM_ * 2);
  unsigned short* W1t_lo = (unsigned short*)walloc((size_t)DH_ * DM_ * 2);
  unsigned short* W2t_hi = (unsigned short*)walloc((size_t)DM_ * DH_ * 2);
  unsigned short* Wqt_hi = (unsigned short*)walloc((size_t)V_ * DM_ * 2);
  unsigned short* Xhi    = (unsigned short*)walloc((size_t)M_ * DM_ * 2);
  unsigned short* Xlo    = (unsigned short*)walloc((size_t)M_ * DM_ * 2);
  unsigned short* S2hi   = (unsigned short*)walloc((size_t)M_ * DM_ * 2);
  float* w2b    = (float*)walloc((DH_ + 1) * 4);
  float* bpart  = (float*)walloc((size_t)M_ * 32 * 4);
  float* pmax   = (float*)walloc((size_t)M_ * PCH_ * 4);
  float* psum   = (float*)walloc((size_t)M_ * PCH_ * 4);
  float* nll    = (float*)walloc(M_ * 4);
  float* bcev   = (float*)walloc(M_ * 4);
  int*   validf = (int*)walloc(M_ * 4);

  float* q_out    = (float*)d_out;
  float* beta_out = q_out + (size_t)M_ * V_;
  float* k_out    = beta_out + M_;
  float* loss_out = k_out + M_;
  unsigned short* act_hi = (unsigned short*)d_out;            // lives in q region
  unsigned short* act_lo = act_hi + (size_t)M_ * DH_;

  // 1) weight transposes + splits
  transpose_split_kernel<<<dim3(DH_ / 32, DM_ / 32), 256, 0, stream>>>(W1, DM_, DH_, W1t_hi, W1t_lo);
  transpose_split_kernel<<<dim3(DM_ / 32, DH_ / 32), 256, 0, stream>>>(W2, DH_, DM_, W2t_hi, nullptr);
  transpose_split_kernel<<<dim3(V_ / 32, DM_ / 32), 256, 0, stream>>>(Wq, DM_, V_, Wqt_hi, nullptr);
  // 2) embed + LN
  embed_ln_kernel<<<M_, 256, 0, stream>>>(H, ids, emb, demb, ln_g, ln_b, Xhi, Xlo);
  // 3) w2b fold
  w2b_kernel<<<DH_ + 1, 64, 0, stream>>>(W2, Wb, b2, bb, w2b);
  // 4) GEMM1 8-phase, split-as-K-concat: K=3072 segs A={Xhi,Xhi,Xlo}, B={W1hi,W1lo,W1hi}
  gemm8p_kernel<true, false, true, false><<<dim3(M_ / 256, DH_ / 256), 512, 0, stream>>>(
      Xhi, Xhi, Xlo, W1t_hi, W1t_lo, W1t_hi, b1, DH_, 3 * DM_,
      nullptr, act_hi, act_lo, nullptr, w2b, bpart, nullptr, nullptr);
  // 5) beta/k/bce from 16 partials
  beta_k_kernel<<<M_, 64, 0, stream>>>(bpart, w2b, mask, beta_out, k_out, bcev, validf);
  // 6) GEMM2: S2 = act @ W2 + b2 (3-deep pipelined 128x128)
  gemm3p_kernel<128, 128, 4, 2><<<dim3(M_ / 128, DM_ / 128), 256, 0, stream>>>(
      act_hi, W2t_hi, b2, DM_, DH_, S2hi);
  // 7) GEMM3 8-phase: q = (S2 @ Wq + bq) * mask, NT stores, CE partials fused
  gemm8p_kernel<false, true, false, true><<<dim3(M_ / 256, V_ / 256), 512, 0, stream>>>(
      S2hi, S2hi, S2hi, Wqt_hi, Wqt_hi, Wqt_hi, bq, V_, DM_,
      q_out, nullptr, nullptr, mask, nullptr, nullptr, pmax, psum);
  // 8) CE combine
  ce_reduce_kernel<<<M_, 64, 0, stream>>>(pmax, psum, q_out, validf, labels, nll);
  // 9) final loss
  loss_kernel<<<1, 256, 0, stream>>>(nll, validf, bcev, loss_out);
}